// Round 4
// baseline (609.132 us; speedup 1.0000x reference)
//
#include <hip/hip_runtime.h>

typedef unsigned short u16;
typedef unsigned int   u32;

typedef short s16x8 __attribute__((ext_vector_type(8)));
typedef float f32x4 __attribute__((ext_vector_type(4)));

__device__ __forceinline__ float b2f(u16 u) {
    u32 x = ((u32)u) << 16;
    float f;
    __builtin_memcpy(&f, &x, 4);
    return f;
}

__device__ __forceinline__ u16 f2b(float f) {
    u32 x;
    __builtin_memcpy(&x, &f, 4);
    u32 r = (x + 0x7fffu + ((x >> 16) & 1u)) >> 16;
    return (u16)r;
}

__device__ __forceinline__ float ldin(const void* p, size_t i, int isf) {
    return isf ? ((const float*)p)[i] : b2f(((const u16*)p)[i]);
}

// ---------------------------------------------------------------------------
// Dtype sniffer: fp32 inputs -> flag[0]=1, bf16 -> flag[0]=0. flag[1]=0.
// ---------------------------------------------------------------------------
__global__ void sniff_kernel(const void* kp, int* flag) {
    if (threadIdx.x == 0) {
        const u16* p = (const u16*)kp;
        int viol = 0;
        for (int i = 0; i < 512; i++) {
            u16 v = p[i];
            if ((v & 0x8000u) || ((v & 0x7FFFu) > 0x3F80u)) viol++;
        }
        flag[0] = (viol > 16) ? 1 : 0;
        flag[1] = 0;
    }
}

// ---------------------------------------------------------------------------
// MFMA C/D-layout probe (verified: matches assumed layout; kept as guard).
// ---------------------------------------------------------------------------
__global__ void probe_mfma(int* __restrict__ map) {
    const int lane = threadIdx.x & 63;
    const int m = lane & 15, q = lane >> 4;
    s16x8 a = (s16x8)0, b = (s16x8)0;
    if (q == 0) {
        a[0] = (short)f2b((float)m);
        a[1] = (short)f2b(1.0f);
        b[0] = (short)f2b(16.0f);
        b[1] = (short)f2b((float)m);
    }
    f32x4 acc = {};
    acc = __builtin_amdgcn_mfma_f32_16x16x32_bf16(a, b, acc, 0, 0, 0);
    #pragma unroll
    for (int i = 0; i < 4; i++)
        map[lane * 4 + i] = ((int)acc[i]) & 255;
}

// ---------------------------------------------------------------------------
// Canonicalize all weights/biases/LN params to bf16 in one region.
// ---------------------------------------------------------------------------
__global__ void convert_params(const void* clw, const void* ihw, const void* cfw,
                               const void* clb, const void* ihb,
                               const void* lnw, const void* lnb, const void* cfb,
                               u16* __restrict__ canon, const int* __restrict__ flag) {
    const int isf = *flag;
    const int total = 2632704;
    for (int i = blockIdx.x * 256 + threadIdx.x; i < total; i += gridDim.x * 256) {
        const void* src; int off;
        if (i < 262144)       { src = clw; off = i; }
        else if (i < 2359296) { src = ihw; off = i - 262144; }
        else if (i < 2621440) { src = cfw; off = i - 2359296; }
        else if (i < 2621952) { src = clb; off = i - 2621440; }
        else if (i < 2624000) { src = ihb; off = i - 2621952; }
        else if (i < 2628096) { src = lnw; off = i - 2624000; }
        else if (i < 2632192) { src = lnb; off = i - 2628096; }
        else                  { src = cfb; off = i - 2632192; }
        canon[i] = isf ? f2b(((const float*)src)[off]) : ((const u16*)src)[off];
    }
}

// ---------------------------------------------------------------------------
// Bilinear interpolation: img[c][n] bf16. One block per channel.
// ---------------------------------------------------------------------------
__global__ void interp_kernel(const void* __restrict__ bev,
                              const void* __restrict__ kp,
                              u16* __restrict__ img,
                              const int* __restrict__ flag) {
    const int isf = *flag;
    const int c = blockIdx.x;
    const size_t pbase = (size_t)c * 65536;
    for (int j = 0; j < 16; j++) {
        const int n = j * 256 + threadIdx.x;
        const float x = ldin(kp, n * 4 + 1, isf) * 256.0f;
        const float y = ldin(kp, n * 4 + 2, isf) * 256.0f;
        const float xf = floorf(x), yf = floorf(y);
        const int x0 = min(max((int)xf, 0), 255);
        const int x1 = min(max((int)xf + 1, 0), 255);
        const int y0 = min(max((int)yf, 0), 255);
        const int y1 = min(max((int)yf + 1, 0), 255);
        const float x0f = (float)x0, x1f = (float)x1;
        const float y0f = (float)y0, y1f = (float)y1;
        const float wa = (x1f - x) * (y1f - y);
        const float wb = (x1f - x) * (y - y0f);
        const float wc = (x - x0f) * (y1f - y);
        const float wd = (x - x0f) * (y - y0f);
        const float Ia = ldin(bev, pbase + y0 * 256 + x0, isf);
        const float Ib = ldin(bev, pbase + y1 * 256 + x0, isf);
        const float Ic = ldin(bev, pbase + y0 * 256 + x1, isf);
        const float Id = ldin(bev, pbase + y1 * 256 + x1, isf);
        img[(size_t)c * 4096 + n] = f2b(Ia * wa + Ib * wb + Ic * wc + Id * wd);
    }
}

// ---------------------------------------------------------------------------
// Transpose (dual-dtype in -> bf16 out): in[R][C] -> out[C][R].
// ---------------------------------------------------------------------------
__global__ void transpose_any(const void* __restrict__ in, u16* __restrict__ out,
                              int R, int C, const int* __restrict__ flag) {
    const int isf = *flag;
    __shared__ u16 tile[64][65];
    const int t = threadIdx.x;
    const int r0 = blockIdx.y * 64, c0 = blockIdx.x * 64;
    #pragma unroll
    for (int i = 0; i < 16; i++) {
        int idx = i * 256 + t;
        int r = idx >> 6, c = idx & 63;
        tile[r][c] = isf ? f2b(((const float*)in)[(size_t)(r0 + r) * C + c0 + c])
                         : ((const u16*)in)[(size_t)(r0 + r) * C + c0 + c];
    }
    __syncthreads();
    #pragma unroll
    for (int i = 0; i < 16; i++) {
        int idx = i * 256 + t;
        int c = idx >> 6, r = idx & 63;
        out[(size_t)(c0 + c) * R + r0 + r] = tile[r][c];
    }
}

// ---------------------------------------------------------------------------
// MFMA GEMM: C[M][N] = A[M][K]*BT[N][K]^T + bias[m].
// OB=0: fp32 out. OB=1: bf16 out. OB=2: per-flag (fp32 if *oflag else bf16).
// ---------------------------------------------------------------------------
template <int OB>
__global__ __launch_bounds__(256) void gemm_bt(const u16* __restrict__ A,
                                               const u16* __restrict__ BT,
                                               const u16* __restrict__ bias,
                                               void* __restrict__ Cout,
                                               const int* __restrict__ mapp,
                                               const int* __restrict__ oflag,
                                               int M, int N, int K) {
    __shared__ __align__(16) u16 As[128 * 40];
    __shared__ __align__(16) u16 Bs[128 * 40];
    const int tid = threadIdx.x;
    const int lane = tid & 63;
    const int w = tid >> 6;
    const int m0 = blockIdx.y * 128;
    const int n0 = blockIdx.x * 128;
    const int wm = (w >> 1) * 64;
    const int wn = (w & 1) * 64;

    f32x4 acc[4][4] = {};

    for (int k0 = 0; k0 < K; k0 += 32) {
        __syncthreads();
        #pragma unroll
        for (int i = 0; i < 2; i++) {
            int s = i * 256 + tid;
            int row = s >> 2, kc = s & 3;
            *(uint4*)&As[row * 40 + kc * 8] =
                *(const uint4*)&A[(size_t)(m0 + row) * K + k0 + kc * 8];
            *(uint4*)&Bs[row * 40 + kc * 8] =
                *(const uint4*)&BT[(size_t)(n0 + row) * K + k0 + kc * 8];
        }
        __syncthreads();

        const int q = lane >> 4, r = lane & 15;
        s16x8 af[4], bfr[4];
        #pragma unroll
        for (int mt = 0; mt < 4; mt++)
            af[mt] = *(const s16x8*)&As[(wm + mt * 16 + r) * 40 + q * 8];
        #pragma unroll
        for (int nt = 0; nt < 4; nt++)
            bfr[nt] = *(const s16x8*)&Bs[(wn + nt * 16 + r) * 40 + q * 8];
        #pragma unroll
        for (int mt = 0; mt < 4; mt++)
            #pragma unroll
            for (int nt = 0; nt < 4; nt++)
                acc[mt][nt] = __builtin_amdgcn_mfma_f32_16x16x32_bf16(
                    af[mt], bfr[nt], acc[mt][nt], 0, 0, 0);
    }

    const int isf = (OB == 2) ? *oflag : 0;
    int prow[4], pcol[4];
    #pragma unroll
    for (int i = 0; i < 4; i++) {
        int mv = mapp[lane * 4 + i] & 255;
        prow[i] = mv >> 4;
        pcol[i] = mv & 15;
    }
    #pragma unroll
    for (int mt = 0; mt < 4; mt++) {
        #pragma unroll
        for (int i = 0; i < 4; i++) {
            int gm = m0 + wm + mt * 16 + prow[i];
            float bv = b2f(bias[gm]);
            #pragma unroll
            for (int nt = 0; nt < 4; nt++) {
                int gn = n0 + wn + nt * 16 + pcol[i];
                float v = acc[mt][nt][i] + bv;
                size_t idx = (size_t)gm * N + gn;
                if (OB == 0)
                    ((float*)Cout)[idx] = v;
                else if (OB == 1)
                    ((u16*)Cout)[idx] = f2b(v);
                else {
                    if (isf) ((float*)Cout)[idx] = v;
                    else     ((u16*)Cout)[idx] = f2b(v);
                }
            }
        }
    }
}

// ---------------------------------------------------------------------------
__global__ void score_partial(const u16* __restrict__ keys,
                              const float* __restrict__ lq,
                              float* __restrict__ spart) {
    __shared__ float red[4][4][64];
    const int nl = threadIdx.x & 63;
    const int ls = threadIdx.x >> 6;
    const int n = blockIdx.x * 64 + nl;
    const int lbase = blockIdx.y * 128 + ls * 32;
    float acc[4] = {0.f, 0.f, 0.f, 0.f};
    for (int i = 0; i < 32; i++) {
        const int l = lbase + i;
        const float qv = lq[l * 4096 + n];
        #pragma unroll
        for (int h = 0; h < 4; h++)
            acc[h] += b2f(keys[(size_t)(h * 512 + l) * 4096 + n]) * qv;
    }
    #pragma unroll
    for (int h = 0; h < 4; h++) red[h][ls][nl] = acc[h];
    __syncthreads();
    if (threadIdx.x < 64) {
        #pragma unroll
        for (int h = 0; h < 4; h++) {
            float s = red[h][0][nl] + red[h][1][nl] + red[h][2][nl] + red[h][3][nl];
            spart[(size_t)(blockIdx.y * 4 + h) * 4096 + n] = s;
        }
    }
}

// ---------------------------------------------------------------------------
// Softmax over heads. Writes wm fp32 to ws and dtype-per-flag to output
// (element offset 2097152 within d_out).
// ---------------------------------------------------------------------------
__global__ void score_finalize(const float* __restrict__ spart,
                               float* __restrict__ wm_ws,
                               void* __restrict__ out,
                               const int* __restrict__ flag) {
    const int isf = *flag;
    const int n = blockIdx.x * 256 + threadIdx.x;
    const float scale = 0.044194173824159216f;  // 1/sqrt(512)
    float s[4];
    #pragma unroll
    for (int h = 0; h < 4; h++) {
        float v = 0.f;
        #pragma unroll
        for (int lc = 0; lc < 4; lc++) v += spart[(size_t)(lc * 4 + h) * 4096 + n];
        s[h] = v * scale;
    }
    float mx = fmaxf(fmaxf(s[0], s[1]), fmaxf(s[2], s[3]));
    float e[4], sum = 0.f;
    #pragma unroll
    for (int h = 0; h < 4; h++) { e[h] = expf(s[h] - mx); sum += e[h]; }
    const float inv = 1.0f / sum;
    #pragma unroll
    for (int h = 0; h < 4; h++) {
        float wv = e[h] * inv;
        wm_ws[h * 4096 + n] = wv;
        size_t idx = 2097152 + (size_t)h * 4096 + n;
        if (isf) ((float*)out)[idx] = wv;
        else     ((u16*)out)[idx]   = f2b(wv);
    }
}

__global__ void compute_t(const u16* __restrict__ keys,
                          const float* __restrict__ lq,
                          const float* __restrict__ wm_ws,
                          float* __restrict__ tbuf) {
    const int n = blockIdx.x * 256 + threadIdx.x;
    const int l = blockIdx.y;
    float t = lq[l * 4096 + n];
    #pragma unroll
    for (int h = 0; h < 4; h++)
        t += wm_ws[h * 4096 + n] * b2f(keys[(size_t)(h * 512 + l) * 4096 + n]);
    tbuf[l * 4096 + n] = t;
}

__global__ void ln_stats(const float* __restrict__ tbuf,
                         float* __restrict__ mu, float* __restrict__ rstd) {
    const int l = blockIdx.x;
    const float* row = tbuf + (size_t)l * 4096;
    float s = 0.f, ss = 0.f;
    for (int i = threadIdx.x; i < 4096; i += 256) {
        float v = row[i];
        s += v;
        ss += v * v;
    }
    for (int off = 32; off > 0; off >>= 1) {
        s += __shfl_down(s, off);
        ss += __shfl_down(ss, off);
    }
    __shared__ float bs[4], bss[4];
    const int w = threadIdx.x >> 6, lane = threadIdx.x & 63;
    if (lane == 0) { bs[w] = s; bss[w] = ss; }
    __syncthreads();
    if (threadIdx.x == 0) {
        s = bs[0] + bs[1] + bs[2] + bs[3];
        ss = bss[0] + bss[1] + bss[2] + bss[3];
        float m = s * (1.0f / 4096.0f);
        float var = ss * (1.0f / 4096.0f) - m * m;
        mu[l] = m;
        rstd[l] = rsqrtf(var + 1e-5f);
    }
}

__global__ void ln_norm_transpose(const float* __restrict__ tbuf,
                                  const float* __restrict__ mu,
                                  const float* __restrict__ rstd,
                                  const u16* __restrict__ lnw,
                                  const u16* __restrict__ lnb,
                                  u16* __restrict__ out) {
    __shared__ float tile[64][65];
    const int t = threadIdx.x;
    const int r0 = blockIdx.y * 64, c0 = blockIdx.x * 64;
    #pragma unroll
    for (int i = 0; i < 16; i++) {
        int idx = i * 256 + t;
        int r = idx >> 6, c = idx & 63;
        float v = tbuf[(size_t)(r0 + r) * 4096 + c0 + c];
        v = (v - mu[r0 + r]) * rstd[r0 + r] * b2f(lnw[c0 + c]) + b2f(lnb[c0 + c]);
        tile[r][c] = v;
    }
    __syncthreads();
    #pragma unroll
    for (int i = 0; i < 16; i++) {
        int idx = i * 256 + t;
        int c = idx >> 6, r = idx & 63;
        out[(size_t)(c0 + c) * 512 + r0 + r] = f2b(tile[r][c]);
    }
}

// ---------------------------------------------------------------------------
extern "C" void kernel_launch(void* const* d_in, const int* in_sizes, int n_in,
                              void* d_out, int out_size, void* d_ws, size_t ws_size,
                              hipStream_t stream) {
    const void* pf  = d_in[0];
    const void* kp  = d_in[1];
    const void* bev = d_in[2];
    const void* clw = d_in[3];
    const void* clb = d_in[4];
    const void* ihw = d_in[5];
    const void* ihb = d_in[6];
    const void* lnw = d_in[7];
    const void* lnb = d_in[8];
    const void* cfw = d_in[9];
    const void* cfb = d_in[10];

    char* ws = (char*)d_ws;
    u16*   img   = (u16*)(ws + 0);
    float* tbuf  = (float*)(ws + 0);
    u16*   imgT  = (u16*)(ws + (8ull << 20));
    float* lq    = (float*)(ws + (8ull << 20));
    u16*   keys  = (u16*)(ws + (16ull << 20));
    u16*   pfT   = (u16*)(ws + (32ull << 20));
    u16*   tT    = (u16*)(ws + (32ull << 20));
    float* spart = (float*)(ws + (36ull << 20));
    float* wm_ws = (float*)(ws + (36ull << 20) + 262144);
    float* mu    = (float*)(ws + (36ull << 20) + 327680);
    float* rstd  = (float*)(ws + (36ull << 20) + 329728);
    int*   flag  = (int*)  (ws + (36ull << 20) + 331776);
    int*   mapp  = (int*)  (ws + (36ull << 20) + 331840);
    u16*   canon = (u16*)  (ws + (36ull << 20) + 332864);

    u16* clw_c = canon;
    u16* ihw_c = canon + 262144;
    u16* cfw_c = canon + 2359296;
    u16* clb_c = canon + 2621440;
    u16* ihb_c = canon + 2621952;
    u16* lnw_c = canon + 2624000;
    u16* lnb_c = canon + 2628096;
    u16* cfb_c = canon + 2632192;

    sniff_kernel<<<1, 64, 0, stream>>>(kp, flag);
    probe_mfma<<<1, 64, 0, stream>>>(mapp);
    convert_params<<<2048, 256, 0, stream>>>(clw, ihw, cfw, clb, ihb, lnw, lnb, cfb,
                                             canon, flag);
    interp_kernel<<<1024, 256, 0, stream>>>(bev, kp, img, flag);
    transpose_any<<<dim3(64, 16), 256, 0, stream>>>(img, imgT, 1024, 4096, flag + 1);
    transpose_any<<<dim3(64, 8), 256, 0, stream>>>(pf, pfT, 512, 4096, flag);
    gemm_bt<1><<<dim3(32, 16), 256, 0, stream>>>(ihw_c, imgT, ihb_c, keys, mapp, flag,
                                                 2048, 4096, 1024);
    gemm_bt<0><<<dim3(32, 4), 256, 0, stream>>>(clw_c, pfT, clb_c, lq, mapp, flag,
                                                512, 4096, 512);
    score_partial<<<dim3(64, 4), 256, 0, stream>>>(keys, lq, spart);
    score_finalize<<<16, 256, 0, stream>>>(spart, wm_ws, d_out, flag);
    compute_t<<<dim3(16, 512), 256, 0, stream>>>(keys, lq, wm_ws, tbuf);
    ln_stats<<<512, 256, 0, stream>>>(tbuf, mu, rstd);
    ln_norm_transpose<<<dim3(64, 8), 256, 0, stream>>>(tbuf, mu, rstd, lnw_c, lnb_c, tT);
    // fusion output: dtype per flag (fp32 if inputs fp32, else bf16)
    gemm_bt<2><<<dim3(32, 4), 256, 0, stream>>>(cfw_c, tT, cfb_c, d_out, mapp, flag,
                                                512, 4096, 512);
}

// Round 5
// 518.800 us; speedup vs baseline: 1.1741x; 1.1741x over previous
//
#include <hip/hip_runtime.h>

typedef unsigned short u16;
typedef unsigned int   u32;

typedef short s16x8 __attribute__((ext_vector_type(8)));
typedef float f32x4 __attribute__((ext_vector_type(4)));

__device__ __forceinline__ float b2f(u16 u) {
    u32 x = ((u32)u) << 16;
    float f;
    __builtin_memcpy(&f, &x, 4);
    return f;
}

__device__ __forceinline__ u16 f2b(float f) {
    u32 x;
    __builtin_memcpy(&x, &f, 4);
    u32 r = (x + 0x7fffu + ((x >> 16) & 1u)) >> 16;
    return (u16)r;
}

// ---------------------------------------------------------------------------
// prep_points: one block, 256 threads. For each keypoint: compute clamped
// bilinear corners + weights (identical math to the verified round-4 interp),
// then counting-sort points into 256 spatial buckets (tile = 32x8 px = one
// 128B fp32 line x 8 rows) so the gather kernel's lanes hit few cache lines.
// Outputs: pts_off[i] (4 corner offsets), pts_w[i] (4 weights), perm[i] = n.
// ---------------------------------------------------------------------------
__global__ void prep_points(const float* __restrict__ kp,
                            int4* __restrict__ pts_off,
                            float4* __restrict__ pts_w,
                            int* __restrict__ perm) {
    __shared__ int cnt[256];
    __shared__ int base[256];
    const int t = threadIdx.x;
    cnt[t] = 0;
    __syncthreads();
    int buck[16];
    #pragma unroll
    for (int j = 0; j < 16; j++) {
        const int n = j * 256 + t;
        const float x = kp[n * 4 + 1] * 256.0f;
        const float y = kp[n * 4 + 2] * 256.0f;
        const int x0 = min(max((int)floorf(x), 0), 255);
        const int y0 = min(max((int)floorf(y), 0), 255);
        const int b = (y0 >> 3) * 8 + (x0 >> 5);
        buck[j] = b;
        atomicAdd(&cnt[b], 1);
    }
    __syncthreads();
    if (t == 0) {
        int s = 0;
        for (int i = 0; i < 256; i++) { base[i] = s; s += cnt[i]; }
    }
    __syncthreads();
    cnt[t] = 0;
    __syncthreads();
    #pragma unroll
    for (int j = 0; j < 16; j++) {
        const int n = j * 256 + t;
        const float x = kp[n * 4 + 1] * 256.0f;
        const float y = kp[n * 4 + 2] * 256.0f;
        const float xf = floorf(x), yf = floorf(y);
        const int x0 = min(max((int)xf, 0), 255);
        const int x1 = min(max((int)xf + 1, 0), 255);
        const int y0 = min(max((int)yf, 0), 255);
        const int y1 = min(max((int)yf + 1, 0), 255);
        const float x0f = (float)x0, x1f = (float)x1;
        const float y0f = (float)y0, y1f = (float)y1;
        float4 w;
        w.x = (x1f - x) * (y1f - y);
        w.y = (x1f - x) * (y - y0f);
        w.z = (x - x0f) * (y1f - y);
        w.w = (x - x0f) * (y - y0f);
        int4 o;
        o.x = y0 * 256 + x0;
        o.y = y1 * 256 + x0;
        o.z = y0 * 256 + x1;
        o.w = y1 * 256 + x1;
        const int b = buck[j];
        const int pos = base[b] + atomicAdd(&cnt[b], 1);
        perm[pos] = n;
        pts_off[pos] = o;
        pts_w[pos] = w;
    }
}

// ---------------------------------------------------------------------------
// interp_sorted: one block per channel; threads walk points in spatially
// sorted order -> gathers hit few 128B lines (L1-resident bucket tiles).
// Writes img[c][slot] bf16 (sorted order; un-permuted by the transpose).
// ---------------------------------------------------------------------------
__global__ __launch_bounds__(256) void interp_sorted(const float* __restrict__ bev,
                                                     const int4* __restrict__ pts_off,
                                                     const float4* __restrict__ pts_w,
                                                     u16* __restrict__ img) {
    const int c = blockIdx.x;
    const float* plane = bev + (size_t)c * 65536;
    const int t = threadIdx.x;
    #pragma unroll
    for (int j = 0; j < 16; j++) {
        const int i = j * 256 + t;
        const int4 o = pts_off[i];
        const float4 w = pts_w[i];
        const float v = plane[o.x] * w.x + plane[o.y] * w.y +
                        plane[o.z] * w.z + plane[o.w] * w.w;
        img[(size_t)c * 4096 + i] = f2b(v);
    }
}

// ---------------------------------------------------------------------------
// Canonicalize weights/biases/LN params fp32 -> bf16 in one region.
// ---------------------------------------------------------------------------
__global__ void convert_params(const float* clw, const float* ihw, const float* cfw,
                               const float* clb, const float* ihb,
                               const float* lnw, const float* lnb, const float* cfb,
                               u16* __restrict__ canon) {
    const int total = 2632704;
    for (int i = blockIdx.x * 256 + threadIdx.x; i < total; i += gridDim.x * 256) {
        const float* src; int off;
        if (i < 262144)       { src = clw; off = i; }
        else if (i < 2359296) { src = ihw; off = i - 262144; }
        else if (i < 2621440) { src = cfw; off = i - 2359296; }
        else if (i < 2621952) { src = clb; off = i - 2621440; }
        else if (i < 2624000) { src = ihb; off = i - 2621952; }
        else if (i < 2628096) { src = lnw; off = i - 2624000; }
        else if (i < 2632192) { src = lnb; off = i - 2628096; }
        else                  { src = cfb; off = i - 2632192; }
        canon[i] = f2b(src[off]);
    }
}

// ---------------------------------------------------------------------------
// Transpose: in[R][C] -> out[perm(C)][R] bf16. ISF=1: fp32 input, ISF=0: u16.
// perm==nullptr -> identity. 64x64 LDS tiles (pad 65).
// ---------------------------------------------------------------------------
template <int ISF>
__global__ void transpose_any(const void* __restrict__ in, u16* __restrict__ out,
                              int R, int C, const int* __restrict__ perm) {
    __shared__ u16 tile[64][65];
    const int t = threadIdx.x;
    const int r0 = blockIdx.y * 64, c0 = blockIdx.x * 64;
    #pragma unroll
    for (int i = 0; i < 16; i++) {
        int idx = i * 256 + t;
        int r = idx >> 6, c = idx & 63;
        tile[r][c] = ISF ? f2b(((const float*)in)[(size_t)(r0 + r) * C + c0 + c])
                         : ((const u16*)in)[(size_t)(r0 + r) * C + c0 + c];
    }
    __syncthreads();
    #pragma unroll
    for (int i = 0; i < 16; i++) {
        int idx = i * 256 + t;
        int c = idx >> 6, r = idx & 63;
        int row = perm ? perm[c0 + c] : (c0 + c);
        out[(size_t)row * R + r0 + r] = tile[r][c];
    }
}

// ---------------------------------------------------------------------------
// MFMA GEMM: C[M][N] = A[M][K]*BT[N][K]^T + bias[m]. bf16 in, fp32 acc.
// 128x128 tile, BK=32, 4 waves, 4x4 16x16x32 MFMAs. C/D layout verified by
// round-3 probe: row = (lane>>4)*4 + reg, col = lane&15.
// OB=0: fp32 out; OB=1: bf16 out. grid dim3(N/128, M/128), 256 threads.
// ---------------------------------------------------------------------------
template <int OB>
__global__ __launch_bounds__(256) void gemm_bt(const u16* __restrict__ A,
                                               const u16* __restrict__ BT,
                                               const u16* __restrict__ bias,
                                               void* __restrict__ Cout,
                                               int M, int N, int K) {
    __shared__ __align__(16) u16 As[128 * 40];
    __shared__ __align__(16) u16 Bs[128 * 40];
    const int tid = threadIdx.x;
    const int lane = tid & 63;
    const int w = tid >> 6;
    const int m0 = blockIdx.y * 128;
    const int n0 = blockIdx.x * 128;
    const int wm = (w >> 1) * 64;
    const int wn = (w & 1) * 64;

    f32x4 acc[4][4] = {};

    for (int k0 = 0; k0 < K; k0 += 32) {
        __syncthreads();
        #pragma unroll
        for (int i = 0; i < 2; i++) {
            int s = i * 256 + tid;
            int row = s >> 2, kc = s & 3;
            *(uint4*)&As[row * 40 + kc * 8] =
                *(const uint4*)&A[(size_t)(m0 + row) * K + k0 + kc * 8];
            *(uint4*)&Bs[row * 40 + kc * 8] =
                *(const uint4*)&BT[(size_t)(n0 + row) * K + k0 + kc * 8];
        }
        __syncthreads();

        const int q = lane >> 4, r = lane & 15;
        s16x8 af[4], bfr[4];
        #pragma unroll
        for (int mt = 0; mt < 4; mt++)
            af[mt] = *(const s16x8*)&As[(wm + mt * 16 + r) * 40 + q * 8];
        #pragma unroll
        for (int nt = 0; nt < 4; nt++)
            bfr[nt] = *(const s16x8*)&Bs[(wn + nt * 16 + r) * 40 + q * 8];
        #pragma unroll
        for (int mt = 0; mt < 4; mt++)
            #pragma unroll
            for (int nt = 0; nt < 4; nt++)
                acc[mt][nt] = __builtin_amdgcn_mfma_f32_16x16x32_bf16(
                    af[mt], bfr[nt], acc[mt][nt], 0, 0, 0);
    }

    const int q = lane >> 4, cn = lane & 15;
    #pragma unroll
    for (int mt = 0; mt < 4; mt++) {
        #pragma unroll
        for (int i = 0; i < 4; i++) {
            int gm = m0 + wm + mt * 16 + q * 4 + i;
            float bv = b2f(bias[gm]);
            #pragma unroll
            for (int nt = 0; nt < 4; nt++) {
                int gn = n0 + wn + nt * 16 + cn;
                float v = acc[mt][nt][i] + bv;
                if (OB)
                    ((u16*)Cout)[(size_t)gm * N + gn] = f2b(v);
                else
                    ((float*)Cout)[(size_t)gm * N + gn] = v;
            }
        }
    }
}

// ---------------------------------------------------------------------------
__global__ void score_partial(const u16* __restrict__ keys,
                              const float* __restrict__ lq,
                              float* __restrict__ spart) {
    __shared__ float red[4][4][64];
    const int nl = threadIdx.x & 63;
    const int ls = threadIdx.x >> 6;
    const int n = blockIdx.x * 64 + nl;
    const int lbase = blockIdx.y * 128 + ls * 32;
    float acc[4] = {0.f, 0.f, 0.f, 0.f};
    for (int i = 0; i < 32; i++) {
        const int l = lbase + i;
        const float qv = lq[l * 4096 + n];
        #pragma unroll
        for (int h = 0; h < 4; h++)
            acc[h] += b2f(keys[(size_t)(h * 512 + l) * 4096 + n]) * qv;
    }
    #pragma unroll
    for (int h = 0; h < 4; h++) red[h][ls][nl] = acc[h];
    __syncthreads();
    if (threadIdx.x < 64) {
        #pragma unroll
        for (int h = 0; h < 4; h++) {
            float s = red[h][0][nl] + red[h][1][nl] + red[h][2][nl] + red[h][3][nl];
            spart[(size_t)(blockIdx.y * 4 + h) * 4096 + n] = s;
        }
    }
}

// ---------------------------------------------------------------------------
// Softmax over heads; wm -> ws (fp32) and d_out region 2 (fp32).
// ---------------------------------------------------------------------------
__global__ void score_finalize(const float* __restrict__ spart,
                               float* __restrict__ wm_ws,
                               float* __restrict__ out) {
    const int n = blockIdx.x * 256 + threadIdx.x;
    const float scale = 0.044194173824159216f;  // 1/sqrt(512)
    float s[4];
    #pragma unroll
    for (int h = 0; h < 4; h++) {
        float v = 0.f;
        #pragma unroll
        for (int lc = 0; lc < 4; lc++) v += spart[(size_t)(lc * 4 + h) * 4096 + n];
        s[h] = v * scale;
    }
    float mx = fmaxf(fmaxf(s[0], s[1]), fmaxf(s[2], s[3]));
    float e[4], sum = 0.f;
    #pragma unroll
    for (int h = 0; h < 4; h++) { e[h] = expf(s[h] - mx); sum += e[h]; }
    const float inv = 1.0f / sum;
    #pragma unroll
    for (int h = 0; h < 4; h++) {
        float wv = e[h] * inv;
        wm_ws[h * 4096 + n] = wv;
        out[2097152 + (size_t)h * 4096 + n] = wv;
    }
}

__global__ void compute_t(const u16* __restrict__ keys,
                          const float* __restrict__ lq,
                          const float* __restrict__ wm_ws,
                          float* __restrict__ tbuf) {
    const int n = blockIdx.x * 256 + threadIdx.x;
    const int l = blockIdx.y;
    float t = lq[l * 4096 + n];
    #pragma unroll
    for (int h = 0; h < 4; h++)
        t += wm_ws[h * 4096 + n] * b2f(keys[(size_t)(h * 512 + l) * 4096 + n]);
    tbuf[l * 4096 + n] = t;
}

__global__ void ln_stats(const float* __restrict__ tbuf,
                         float* __restrict__ mu, float* __restrict__ rstd) {
    const int l = blockIdx.x;
    const float* row = tbuf + (size_t)l * 4096;
    float s = 0.f, ss = 0.f;
    for (int i = threadIdx.x; i < 4096; i += 256) {
        float v = row[i];
        s += v;
        ss += v * v;
    }
    for (int off = 32; off > 0; off >>= 1) {
        s += __shfl_down(s, off);
        ss += __shfl_down(ss, off);
    }
    __shared__ float bs[4], bss[4];
    const int w = threadIdx.x >> 6, lane = threadIdx.x & 63;
    if (lane == 0) { bs[w] = s; bss[w] = ss; }
    __syncthreads();
    if (threadIdx.x == 0) {
        s = bs[0] + bs[1] + bs[2] + bs[3];
        ss = bss[0] + bss[1] + bss[2] + bss[3];
        float m = s * (1.0f / 4096.0f);
        float var = ss * (1.0f / 4096.0f) - m * m;
        mu[l] = m;
        rstd[l] = rsqrtf(var + 1e-5f);
    }
}

__global__ void ln_norm_transpose(const float* __restrict__ tbuf,
                                  const float* __restrict__ mu,
                                  const float* __restrict__ rstd,
                                  const u16* __restrict__ lnw,
                                  const u16* __restrict__ lnb,
                                  u16* __restrict__ out) {
    __shared__ float tile[64][65];
    const int t = threadIdx.x;
    const int r0 = blockIdx.y * 64, c0 = blockIdx.x * 64;
    #pragma unroll
    for (int i = 0; i < 16; i++) {
        int idx = i * 256 + t;
        int r = idx >> 6, c = idx & 63;
        float v = tbuf[(size_t)(r0 + r) * 4096 + c0 + c];
        v = (v - mu[r0 + r]) * rstd[r0 + r] * b2f(lnw[c0 + c]) + b2f(lnb[c0 + c]);
        tile[r][c] = v;
    }
    __syncthreads();
    #pragma unroll
    for (int i = 0; i < 16; i++) {
        int idx = i * 256 + t;
        int c = idx >> 6, r = idx & 63;
        out[(size_t)(c0 + c) * 512 + r0 + r] = f2b(tile[r][c]);
    }
}

// ---------------------------------------------------------------------------
extern "C" void kernel_launch(void* const* d_in, const int* in_sizes, int n_in,
                              void* d_out, int out_size, void* d_ws, size_t ws_size,
                              hipStream_t stream) {
    const float* pf  = (const float*)d_in[0];
    const float* kp  = (const float*)d_in[1];
    const float* bev = (const float*)d_in[2];
    const float* clw = (const float*)d_in[3];
    const float* clb = (const float*)d_in[4];
    const float* ihw = (const float*)d_in[5];
    const float* ihb = (const float*)d_in[6];
    const float* lnw = (const float*)d_in[7];
    const float* lnb = (const float*)d_in[8];
    const float* cfw = (const float*)d_in[9];
    const float* cfb = (const float*)d_in[10];
    float* out = (float*)d_out;

    char* ws = (char*)d_ws;
    u16*    img     = (u16*)(ws + 0);                    // 8 MB (1024,4096) sorted
    float*  tbuf    = (float*)(ws + 0);                  // reuse after transpose
    u16*    imgT    = (u16*)(ws + (8ull << 20));         // 8 MB (4096,1024)
    float*  lq      = (float*)(ws + (8ull << 20));       // reuse after keys gemm
    u16*    keys    = (u16*)(ws + (16ull << 20));        // 16 MB (2048,4096)
    u16*    pfT     = (u16*)(ws + (32ull << 20));        // 4 MB (4096,512)
    u16*    tT      = (u16*)(ws + (32ull << 20));        // reuse
    float*  spart   = (float*)(ws + (36ull << 20));
    float*  wm_ws   = (float*)(ws + (36ull << 20) + 262144);
    float*  mu      = (float*)(ws + (36ull << 20) + 327680);
    float*  rstd    = (float*)(ws + (36ull << 20) + 329728);
    u16*    canon   = (u16*)  (ws + (36ull << 20) + 332864);  // 5.03 MB
    int4*   pts_off = (int4*) (ws + (42ull << 20));           // 64 KB
    float4* pts_w   = (float4*)(ws + (42ull << 20) + 65536);  // 64 KB
    int*    perm    = (int*)  (ws + (42ull << 20) + 131072);  // 16 KB

    u16* clw_c = canon;
    u16* ihw_c = canon + 262144;
    u16* cfw_c = canon + 2359296;
    u16* clb_c = canon + 2621440;
    u16* ihb_c = canon + 2621952;
    u16* lnw_c = canon + 2624000;
    u16* lnb_c = canon + 2628096;
    u16* cfb_c = canon + 2632192;

    prep_points<<<1, 256, 0, stream>>>(kp, pts_off, pts_w, perm);
    convert_params<<<1024, 256, 0, stream>>>(clw, ihw, cfw, clb, ihb, lnw, lnb, cfb, canon);
    interp_sorted<<<1024, 256, 0, stream>>>(bev, pts_off, pts_w, img);
    transpose_any<0><<<dim3(64, 16), 256, 0, stream>>>(img, imgT, 1024, 4096, perm);
    transpose_any<1><<<dim3(64, 8), 256, 0, stream>>>(pf, pfT, 512, 4096, nullptr);
    gemm_bt<1><<<dim3(32, 16), 256, 0, stream>>>(ihw_c, imgT, ihb_c, keys, 2048, 4096, 1024);
    gemm_bt<0><<<dim3(32, 4), 256, 0, stream>>>(clw_c, pfT, clb_c, lq, 512, 4096, 512);
    score_partial<<<dim3(64, 4), 256, 0, stream>>>(keys, lq, spart);
    score_finalize<<<16, 256, 0, stream>>>(spart, wm_ws, out);
    compute_t<<<dim3(16, 512), 256, 0, stream>>>(keys, lq, wm_ws, tbuf);
    ln_stats<<<512, 256, 0, stream>>>(tbuf, mu, rstd);
    ln_norm_transpose<<<dim3(64, 8), 256, 0, stream>>>(tbuf, mu, rstd, lnw_c, lnb_c, tT);
    gemm_bt<0><<<dim3(32, 4), 256, 0, stream>>>(cfw_c, tT, cfb_c, out, 512, 4096, 512);
}

// Round 6
// 511.686 us; speedup vs baseline: 1.1904x; 1.0139x over previous
//
#include <hip/hip_runtime.h>

typedef unsigned short u16;
typedef unsigned int   u32;

typedef short s16x8 __attribute__((ext_vector_type(8)));
typedef float f32x4 __attribute__((ext_vector_type(4)));

__device__ __forceinline__ float b2f(u16 u) {
    u32 x = ((u32)u) << 16;
    float f;
    __builtin_memcpy(&f, &x, 4);
    return f;
}

__device__ __forceinline__ u16 f2b(float f) {
    u32 x;
    __builtin_memcpy(&x, &f, 4);
    u32 r = (x + 0x7fffu + ((x >> 16) & 1u)) >> 16;
    return (u16)r;
}

// ---------------------------------------------------------------------------
// prep_points: one block, 256 threads. Bilinear corners + weights per point,
// then counting-sort into 256 spatial buckets (32x8 px tiles). Prefix sum via
// wave shfl scan (was serial on thread 0).
// ---------------------------------------------------------------------------
__global__ void prep_points(const float* __restrict__ kp,
                            int4* __restrict__ pts_off,
                            float4* __restrict__ pts_w,
                            int* __restrict__ perm) {
    __shared__ int cnt[256];
    __shared__ int base[256];
    const int t = threadIdx.x;
    cnt[t] = 0;
    __syncthreads();
    int buck[16];
    #pragma unroll
    for (int j = 0; j < 16; j++) {
        const int n = j * 256 + t;
        const float x = kp[n * 4 + 1] * 256.0f;
        const float y = kp[n * 4 + 2] * 256.0f;
        const int x0 = min(max((int)floorf(x), 0), 255);
        const int y0 = min(max((int)floorf(y), 0), 255);
        const int b = (y0 >> 3) * 8 + (x0 >> 5);
        buck[j] = b;
        atomicAdd(&cnt[b], 1);
    }
    __syncthreads();
    if (t < 64) {
        int a0 = cnt[t * 4], a1 = cnt[t * 4 + 1], a2 = cnt[t * 4 + 2], a3 = cnt[t * 4 + 3];
        int tot = a0 + a1 + a2 + a3;
        int pre = tot;
        #pragma unroll
        for (int off = 1; off < 64; off <<= 1) {
            int v = __shfl_up(pre, off);
            if (t >= off) pre += v;
        }
        int excl = pre - tot;
        base[t * 4]     = excl;
        base[t * 4 + 1] = excl + a0;
        base[t * 4 + 2] = excl + a0 + a1;
        base[t * 4 + 3] = excl + a0 + a1 + a2;
    }
    __syncthreads();
    cnt[t] = 0;
    __syncthreads();
    #pragma unroll
    for (int j = 0; j < 16; j++) {
        const int n = j * 256 + t;
        const float x = kp[n * 4 + 1] * 256.0f;
        const float y = kp[n * 4 + 2] * 256.0f;
        const float xf = floorf(x), yf = floorf(y);
        const int x0 = min(max((int)xf, 0), 255);
        const int x1 = min(max((int)xf + 1, 0), 255);
        const int y0 = min(max((int)yf, 0), 255);
        const int y1 = min(max((int)yf + 1, 0), 255);
        const float x0f = (float)x0, x1f = (float)x1;
        const float y0f = (float)y0, y1f = (float)y1;
        float4 w;
        w.x = (x1f - x) * (y1f - y);
        w.y = (x1f - x) * (y - y0f);
        w.z = (x - x0f) * (y1f - y);
        w.w = (x - x0f) * (y - y0f);
        int4 o;
        o.x = y0 * 256 + x0;
        o.y = y1 * 256 + x0;
        o.z = y0 * 256 + x1;
        o.w = y1 * 256 + x1;
        const int b = buck[j];
        const int pos = base[b] + atomicAdd(&cnt[b], 1);
        perm[pos] = n;
        pts_off[pos] = o;
        pts_w[pos] = w;
    }
}

// ---------------------------------------------------------------------------
// interp_sorted: grid dim3(1024, 4) — channel x point-quarter (4x TLP vs r5).
// Threads walk spatially sorted points; gathers hit few 128B lines.
// ---------------------------------------------------------------------------
__global__ __launch_bounds__(256) void interp_sorted(const float* __restrict__ bev,
                                                     const int4* __restrict__ pts_off,
                                                     const float4* __restrict__ pts_w,
                                                     u16* __restrict__ img) {
    const int c = blockIdx.x;
    const float* plane = bev + (size_t)c * 65536;
    const int base_i = blockIdx.y * 1024;
    const int t = threadIdx.x;
    #pragma unroll
    for (int j = 0; j < 4; j++) {
        const int i = base_i + j * 256 + t;
        const int4 o = pts_off[i];
        const float4 w = pts_w[i];
        const float v = plane[o.x] * w.x + plane[o.y] * w.y +
                        plane[o.z] * w.z + plane[o.w] * w.w;
        img[(size_t)c * 4096 + i] = f2b(v);
    }
}

// ---------------------------------------------------------------------------
// Canonicalize weights/biases fp32 -> bf16 (lnw/lnb now consumed as fp32
// directly; slots kept for layout stability).
// ---------------------------------------------------------------------------
__global__ void convert_params(const float* clw, const float* ihw, const float* cfw,
                               const float* clb, const float* ihb,
                               const float* lnw, const float* lnb, const float* cfb,
                               u16* __restrict__ canon) {
    const int total = 2632704;
    for (int i = blockIdx.x * 256 + threadIdx.x; i < total; i += gridDim.x * 256) {
        const float* src; int off;
        if (i < 262144)       { src = clw; off = i; }
        else if (i < 2359296) { src = ihw; off = i - 262144; }
        else if (i < 2621440) { src = cfw; off = i - 2359296; }
        else if (i < 2621952) { src = clb; off = i - 2621440; }
        else if (i < 2624000) { src = ihb; off = i - 2621952; }
        else if (i < 2628096) { src = lnw; off = i - 2624000; }
        else if (i < 2632192) { src = lnb; off = i - 2628096; }
        else                  { src = cfb; off = i - 2632192; }
        canon[i] = f2b(src[off]);
    }
}

// ---------------------------------------------------------------------------
// Transpose: in[R][C] -> out[perm(C)][R] bf16. ISF=1: fp32 in; ISF=0: u16 in.
// ---------------------------------------------------------------------------
template <int ISF>
__global__ void transpose_any(const void* __restrict__ in, u16* __restrict__ out,
                              int R, int C, const int* __restrict__ perm) {
    __shared__ u16 tile[64][65];
    const int t = threadIdx.x;
    const int r0 = blockIdx.y * 64, c0 = blockIdx.x * 64;
    #pragma unroll
    for (int i = 0; i < 16; i++) {
        int idx = i * 256 + t;
        int r = idx >> 6, c = idx & 63;
        tile[r][c] = ISF ? f2b(((const float*)in)[(size_t)(r0 + r) * C + c0 + c])
                         : ((const u16*)in)[(size_t)(r0 + r) * C + c0 + c];
    }
    __syncthreads();
    #pragma unroll
    for (int i = 0; i < 16; i++) {
        int idx = i * 256 + t;
        int c = idx >> 6, r = idx & 63;
        int row = perm ? perm[c0 + c] : (c0 + c);
        out[(size_t)row * R + r0 + r] = tile[r][c];
    }
}

// ---------------------------------------------------------------------------
// MFMA GEMM: C[M][N] = A[M][K]*BT[N][K]^T + bias[m]. bf16 in, fp32 acc.
// 128x128 tile, BK=32, 4 waves, 4x4 16x16x32 MFMAs, padded LDS (40/row).
// OB=0: fp32 out; OB=1: bf16 out.
// ---------------------------------------------------------------------------
template <int OB>
__global__ __launch_bounds__(256) void gemm_bt(const u16* __restrict__ A,
                                               const u16* __restrict__ BT,
                                               const u16* __restrict__ bias,
                                               void* __restrict__ Cout,
                                               int M, int N, int K) {
    __shared__ __align__(16) u16 As[128 * 40];
    __shared__ __align__(16) u16 Bs[128 * 40];
    const int tid = threadIdx.x;
    const int lane = tid & 63;
    const int w = tid >> 6;
    const int m0 = blockIdx.y * 128;
    const int n0 = blockIdx.x * 128;
    const int wm = (w >> 1) * 64;
    const int wn = (w & 1) * 64;

    f32x4 acc[4][4] = {};

    for (int k0 = 0; k0 < K; k0 += 32) {
        __syncthreads();
        #pragma unroll
        for (int i = 0; i < 2; i++) {
            int s = i * 256 + tid;
            int row = s >> 2, kc = s & 3;
            *(uint4*)&As[row * 40 + kc * 8] =
                *(const uint4*)&A[(size_t)(m0 + row) * K + k0 + kc * 8];
            *(uint4*)&Bs[row * 40 + kc * 8] =
                *(const uint4*)&BT[(size_t)(n0 + row) * K + k0 + kc * 8];
        }
        __syncthreads();

        const int q = lane >> 4, r = lane & 15;
        s16x8 af[4], bfr[4];
        #pragma unroll
        for (int mt = 0; mt < 4; mt++)
            af[mt] = *(const s16x8*)&As[(wm + mt * 16 + r) * 40 + q * 8];
        #pragma unroll
        for (int nt = 0; nt < 4; nt++)
            bfr[nt] = *(const s16x8*)&Bs[(wn + nt * 16 + r) * 40 + q * 8];
        #pragma unroll
        for (int mt = 0; mt < 4; mt++)
            #pragma unroll
            for (int nt = 0; nt < 4; nt++)
                acc[mt][nt] = __builtin_amdgcn_mfma_f32_16x16x32_bf16(
                    af[mt], bfr[nt], acc[mt][nt], 0, 0, 0);
    }

    const int q = lane >> 4, cn = lane & 15;
    #pragma unroll
    for (int mt = 0; mt < 4; mt++) {
        #pragma unroll
        for (int i = 0; i < 4; i++) {
            int gm = m0 + wm + mt * 16 + q * 4 + i;
            float bv = b2f(bias[gm]);
            #pragma unroll
            for (int nt = 0; nt < 4; nt++) {
                int gn = n0 + wn + nt * 16 + cn;
                float v = acc[mt][nt][i] + bv;
                if (OB)
                    ((u16*)Cout)[(size_t)gm * N + gn] = f2b(v);
                else
                    ((float*)Cout)[(size_t)gm * N + gn] = v;
            }
        }
    }
}

// ---------------------------------------------------------------------------
__global__ void score_partial(const u16* __restrict__ keys,
                              const float* __restrict__ lq,
                              float* __restrict__ spart) {
    __shared__ float red[4][4][64];
    const int nl = threadIdx.x & 63;
    const int ls = threadIdx.x >> 6;
    const int n = blockIdx.x * 64 + nl;
    const int lbase = blockIdx.y * 128 + ls * 32;
    float acc[4] = {0.f, 0.f, 0.f, 0.f};
    for (int i = 0; i < 32; i++) {
        const int l = lbase + i;
        const float qv = lq[l * 4096 + n];
        #pragma unroll
        for (int h = 0; h < 4; h++)
            acc[h] += b2f(keys[(size_t)(h * 512 + l) * 4096 + n]) * qv;
    }
    #pragma unroll
    for (int h = 0; h < 4; h++) red[h][ls][nl] = acc[h];
    __syncthreads();
    if (threadIdx.x < 64) {
        #pragma unroll
        for (int h = 0; h < 4; h++) {
            float s = red[h][0][nl] + red[h][1][nl] + red[h][2][nl] + red[h][3][nl];
            spart[(size_t)(blockIdx.y * 4 + h) * 4096 + n] = s;
        }
    }
}

__global__ void score_finalize(const float* __restrict__ spart,
                               float* __restrict__ wm_ws,
                               float* __restrict__ out) {
    const int n = blockIdx.x * 256 + threadIdx.x;
    const float scale = 0.044194173824159216f;  // 1/sqrt(512)
    float s[4];
    #pragma unroll
    for (int h = 0; h < 4; h++) {
        float v = 0.f;
        #pragma unroll
        for (int lc = 0; lc < 4; lc++) v += spart[(size_t)(lc * 4 + h) * 4096 + n];
        s[h] = v * scale;
    }
    float mx = fmaxf(fmaxf(s[0], s[1]), fmaxf(s[2], s[3]));
    float e[4], sum = 0.f;
    #pragma unroll
    for (int h = 0; h < 4; h++) { e[h] = expf(s[h] - mx); sum += e[h]; }
    const float inv = 1.0f / sum;
    #pragma unroll
    for (int h = 0; h < 4; h++) {
        float wv = e[h] * inv;
        wm_ws[h * 4096 + n] = wv;
        out[2097152 + (size_t)h * 4096 + n] = wv;
    }
}

// ---------------------------------------------------------------------------
// Fused t + LayerNorm: one block per channel l. Computes
// t = lq + sum_h wm*keys (in registers), block-reduces mu/rstd, normalizes
// with fp32 ln_w/ln_b, writes bf16 tnorm[l][n]. Replaces compute_t +
// ln_stats + the fp32 half of ln_norm_transpose.
// ---------------------------------------------------------------------------
__global__ __launch_bounds__(256) void compute_t_ln(const u16* __restrict__ keys,
                                                    const float* __restrict__ lq,
                                                    const float* __restrict__ wm_ws,
                                                    const float* __restrict__ lnw,
                                                    const float* __restrict__ lnb,
                                                    u16* __restrict__ tnorm) {
    const int l = blockIdx.x;
    const int t = threadIdx.x;
    float tv[16];
    float s = 0.f, ss = 0.f;
    #pragma unroll
    for (int j = 0; j < 16; j++) {
        const int n = j * 256 + t;
        float v = lq[l * 4096 + n];
        #pragma unroll
        for (int h = 0; h < 4; h++)
            v += wm_ws[h * 4096 + n] * b2f(keys[(size_t)(h * 512 + l) * 4096 + n]);
        tv[j] = v;
        s += v;
        ss += v * v;
    }
    for (int off = 32; off > 0; off >>= 1) {
        s += __shfl_down(s, off);
        ss += __shfl_down(ss, off);
    }
    __shared__ float bs[4], bss[4];
    const int w = t >> 6, lane = t & 63;
    if (lane == 0) { bs[w] = s; bss[w] = ss; }
    __syncthreads();
    const float S = bs[0] + bs[1] + bs[2] + bs[3];
    const float SS = bss[0] + bss[1] + bss[2] + bss[3];
    const float mu = S * (1.0f / 4096.0f);
    const float rstd = rsqrtf(SS * (1.0f / 4096.0f) - mu * mu + 1e-5f);
    #pragma unroll
    for (int j = 0; j < 16; j++) {
        const int n = j * 256 + t;
        const float v = (tv[j] - mu) * rstd * lnw[n] + lnb[n];
        tnorm[(size_t)l * 4096 + n] = f2b(v);
    }
}

// ---------------------------------------------------------------------------
extern "C" void kernel_launch(void* const* d_in, const int* in_sizes, int n_in,
                              void* d_out, int out_size, void* d_ws, size_t ws_size,
                              hipStream_t stream) {
    const float* pf  = (const float*)d_in[0];
    const float* kp  = (const float*)d_in[1];
    const float* bev = (const float*)d_in[2];
    const float* clw = (const float*)d_in[3];
    const float* clb = (const float*)d_in[4];
    const float* ihw = (const float*)d_in[5];
    const float* ihb = (const float*)d_in[6];
    const float* lnw = (const float*)d_in[7];
    const float* lnb = (const float*)d_in[8];
    const float* cfw = (const float*)d_in[9];
    const float* cfb = (const float*)d_in[10];
    float* out = (float*)d_out;

    char* ws = (char*)d_ws;
    u16*    img     = (u16*)(ws + 0);                    // 8 MB (1024,4096) sorted
    u16*    tnorm   = (u16*)(ws + 0);                    // 4 MB, reuse after T-img
    u16*    imgT    = (u16*)(ws + (8ull << 20));         // 8 MB (4096,1024)
    float*  lq      = (float*)(ws + (8ull << 20));       // 8 MB, reuse after gemm-keys
    u16*    keys    = (u16*)(ws + (16ull << 20));        // 16 MB (2048,4096)
    u16*    pfT     = (u16*)(ws + (32ull << 20));        // 4 MB (4096,512)
    u16*    tT      = (u16*)(ws + (32ull << 20));        // reuse after gemm-lq
    float*  spart   = (float*)(ws + (36ull << 20));
    float*  wm_ws   = (float*)(ws + (36ull << 20) + 262144);
    u16*    canon   = (u16*)  (ws + (36ull << 20) + 332864);  // 5.03 MB
    int4*   pts_off = (int4*) (ws + (42ull << 20));           // 64 KB
    float4* pts_w   = (float4*)(ws + (42ull << 20) + 65536);  // 64 KB
    int*    perm    = (int*)  (ws + (42ull << 20) + 131072);  // 16 KB

    u16* clw_c = canon;
    u16* ihw_c = canon + 262144;
    u16* cfw_c = canon + 2359296;
    u16* clb_c = canon + 2621440;
    u16* ihb_c = canon + 2621952;
    u16* cfb_c = canon + 2632192;

    prep_points<<<1, 256, 0, stream>>>(kp, pts_off, pts_w, perm);
    convert_params<<<1024, 256, 0, stream>>>(clw, ihw, cfw, clb, ihb, lnw, lnb, cfb, canon);
    interp_sorted<<<dim3(1024, 4), 256, 0, stream>>>(bev, pts_off, pts_w, img);
    transpose_any<0><<<dim3(64, 16), 256, 0, stream>>>(img, imgT, 1024, 4096, perm);
    transpose_any<1><<<dim3(64, 8), 256, 0, stream>>>(pf, pfT, 512, 4096, nullptr);
    gemm_bt<1><<<dim3(32, 16), 256, 0, stream>>>(ihw_c, imgT, ihb_c, keys, 2048, 4096, 1024);
    gemm_bt<0><<<dim3(32, 4), 256, 0, stream>>>(clw_c, pfT, clb_c, lq, 512, 4096, 512);
    score_partial<<<dim3(64, 4), 256, 0, stream>>>(keys, lq, spart);
    score_finalize<<<16, 256, 0, stream>>>(spart, wm_ws, out);
    compute_t_ln<<<512, 256, 0, stream>>>(keys, lq, wm_ws, lnw, lnb, tnorm);
    transpose_any<0><<<dim3(64, 8), 256, 0, stream>>>(tnorm, tT, 512, 4096, nullptr);
    gemm_bt<0><<<dim3(32, 4), 256, 0, stream>>>(cfw_c, tT, cfb_c, out, 512, 4096, 512);
}